// Round 11
// baseline (180.975 us; speedup 1.0000x reference)
//
#include <hip/hip_runtime.h>

// EdgeConv (B=2, N=8192, C=64, K=20, OUT=64):
//  zeroh   -> zero z-histogram
//  proj    -> per-point 64->64 projections (8-way split); by==0 also packs
//             cpack=(x,y,z,|c|^2) and builds the z-bucket histogram
//  prefix  -> exclusive prefix over 1024 z-buckets (one block per batch)
//  scatter -> counting-sort into z-order: s4g, sidxg (orig id), rinv (orig->slot)
//  knnfeat -> 512 blocks x 1024 thr (16 waves x 2 queries), ~75 KB LDS ->
//             2 blocks/CU -> 8 waves/SIMD (the latency-bound serial sections
//             -- bisect / fp64 rank / feat gathers -- now overlap across waves).
//             slab(1024)->tau->union window->stage(<=4096)->windowed pass2.
//             Global-memory fallback if window > 4096 (correct, ~never taken).
//             Exact fp64 rank select (ties -> lower orig idx) => deterministic.
//  permute -> scratch[rinv[n]][o] -> out[b][o][n]

#define NPTS 8192
#define NBATCH 2
#define CH 64
#define KNN 20
#define EDIM 197
#define NBUCK 1024
#define CAPC 64
#define KWAVES 16
#define QW 2
#define QB (KWAVES * QW) // 32 queries per block
#define WCAP 4096        // window LDS capacity (measured max ~1500)

__device__ __forceinline__ int zbucket(float z) {
  int b = (int)((z + 4.5f) * (1024.0f / 9.0f));
  return b < 0 ? 0 : (b > 1023 ? 1023 : b);
}

__device__ __forceinline__ float wsum(float v) {
  v += __shfl_xor(v, 1, 64);
  v += __shfl_xor(v, 2, 64);
  v += __shfl_xor(v, 4, 64);
  v += __shfl_xor(v, 8, 64);
  v += __shfl_xor(v, 16, 64);
  v += __shfl_xor(v, 32, 64);
  return v;
}

// monotone-shifted surrogate d~ = |c|^2 - 2 q.c = d^2 - |q|^2 (exact shift);
// identical fmaf chain everywhere -> bitwise-consistent threshold tests
__device__ __forceinline__ float dtilde(float m2x, float m2y, float m2z, float4 c) {
  return fmaf(m2x, c.x, fmaf(m2y, c.y, fmaf(m2z, c.z, c.w)));
}

// exact-enough fp64 distance (fp32 diffs exact in fp64, squares exact)
__device__ __forceinline__ double d2d(float qx, float qy, float qz, float4 c) {
  double dx = (double)qx - (double)c.x;
  double dy = (double)qy - (double)c.y;
  double dz = (double)qz - (double)c.z;
  return dx * dx + dy * dy + dz * dz;
}

__device__ __forceinline__ float bcastf(float v, int l) {
  return __int_as_float(__builtin_amdgcn_readlane(__float_as_int(v), l));
}

__global__ __launch_bounds__(1024) void zeroh_kernel(int* __restrict__ hist) {
  int t = blockIdx.x * 1024 + threadIdx.x;
  if (t < NBATCH * NBUCK) hist[t] = 0;
}

// blockIdx.y in [0,8): mat = by>>2, output-quarter = by&3 (16 channels each).
__global__ __launch_bounds__(256) void proj_kernel(const float* __restrict__ x,
                                                   const float* __restrict__ w,
                                                   float4* __restrict__ cpack,
                                                   float* __restrict__ projc,
                                                   float* __restrict__ projn,
                                                   int* __restrict__ hist) {
  __shared__ float wl[CH * 16];
  int by = blockIdx.y;
  int mat = by >> 2, oq = by & 3;
  for (int i = threadIdx.x; i < CH * 16; i += 256) {
    int c = i >> 4, oo = i & 15;
    int o = oq * 16 + oo;
    float w1 = w[o * EDIM + c];
    float w2 = w[o * EDIM + 64 + c];
    float w3 = w[o * EDIM + 128 + c];
    wl[i] = mat ? (w2 + w3) : (w1 - w2);
  }
  __syncthreads();
  int p = blockIdx.x * 256 + threadIdx.x;
  int b = p >> 13, n = p & (NPTS - 1);
  const float* xb = x + (size_t)b * CH * NPTS + n;
  float acc[16];
#pragma unroll
  for (int o = 0; o < 16; ++o) acc[o] = 0.f;
#pragma unroll 4
  for (int c = 0; c < CH; ++c) {
    float xv = xb[(size_t)c * NPTS];
    const float4* wr = (const float4*)(wl + c * 16);
#pragma unroll
    for (int o4 = 0; o4 < 4; ++o4) {
      float4 wv = wr[o4];
      acc[o4 * 4 + 0] = fmaf(wv.x, xv, acc[o4 * 4 + 0]);
      acc[o4 * 4 + 1] = fmaf(wv.y, xv, acc[o4 * 4 + 1]);
      acc[o4 * 4 + 2] = fmaf(wv.z, xv, acc[o4 * 4 + 2]);
      acc[o4 * 4 + 3] = fmaf(wv.w, xv, acc[o4 * 4 + 3]);
    }
  }
  float* dst = (mat ? projn : projc) + (size_t)p * 64 + oq * 16;
#pragma unroll
  for (int o4 = 0; o4 < 4; ++o4)
    ((float4*)dst)[o4] = make_float4(acc[o4 * 4 + 0], acc[o4 * 4 + 1],
                                     acc[o4 * 4 + 2], acc[o4 * 4 + 3]);
  if (by == 0) {
    float cx = xb[0], cy = xb[(size_t)NPTS], cz = xb[(size_t)2 * NPTS];
    cpack[p] = make_float4(cx, cy, cz, fmaf(cx, cx, fmaf(cy, cy, cz * cz)));
    atomicAdd(&hist[b * NBUCK + zbucket(cz)], 1);
  }
}

__global__ __launch_bounds__(1024) void prefix_kernel(const int* __restrict__ hist,
                                                      int* __restrict__ off,
                                                      int* __restrict__ cursor) {
  __shared__ int s[NBUCK];
  int b = blockIdx.x;
  int tid = threadIdx.x;
  s[tid] = hist[b * NBUCK + tid];
  __syncthreads();
  for (int o = 1; o < NBUCK; o <<= 1) {
    int t = (tid >= o) ? s[tid - o] : 0;
    __syncthreads();
    s[tid] += t;
    __syncthreads();
  }
  int excl = tid ? s[tid - 1] : 0;
  off[b * (NBUCK + 1) + tid] = excl;
  cursor[b * NBUCK + tid] = excl;
  if (tid == NBUCK - 1) off[b * (NBUCK + 1) + NBUCK] = s[NBUCK - 1];
}

__global__ __launch_bounds__(256) void scatter_kernel(const float4* __restrict__ cpack,
                                                      int* __restrict__ cursor,
                                                      float4* __restrict__ s4g,
                                                      int* __restrict__ sidxg,
                                                      int* __restrict__ rinv) {
  int t = blockIdx.x * 256 + threadIdx.x;
  int b = t >> 13, n = t & (NPTS - 1);
  float4 c = cpack[t];
  int slot = atomicAdd(&cursor[b * NBUCK + zbucket(c.z)], 1);
  s4g[b * NPTS + slot] = c;
  sidxg[b * NPTS + slot] = n;
  rinv[b * NPTS + n] = slot;
}

__global__ __launch_bounds__(1024, 8) void knnfeat_kernel(const float4* __restrict__ s4g,
                                                          const int* __restrict__ sidxg,
                                                          const int* __restrict__ off,
                                                          const float* __restrict__ projc,
                                                          const float* __restrict__ projn,
                                                          const float* __restrict__ w,
                                                          const float* __restrict__ gamma,
                                                          const float* __restrict__ beta,
                                                          const float* __restrict__ mean,
                                                          const float* __restrict__ var,
                                                          float* __restrict__ scratch) {
  __shared__ float4 t4[WCAP];                       // 64 KB window buffer
  __shared__ int offL[NBUCK + 1];                   // 4.1 KB
  __shared__ unsigned short lidx[KWAVES][QW][CAPC]; // 4 KB
  __shared__ int nsel[KWAVES][QW][KNN];             // 2.5 KB
  __shared__ int ew0[KWAVES], ew1[KWAVES];          // window-union scratch
  int tid = threadIdx.x, lane = tid & 63, wq = tid >> 6;
  int blk = blockIdx.x;           // 512 blocks, 2/CU
  int bb = blk >> 8;
  int q0b = (blk & 255) * QB;     // block's sorted-query base
  int q0s = q0b + wq * QW;        // this wave's sorted-query base
  const float4* sb = s4g + bb * NPTS;
  const int* ib = sidxg + bb * NPTS;
  unsigned long long lmlt = (1ull << lane) - 1ull;

  // ---- stage A: 1024-slab around the block's queries (pass1 subset)
  int sA = q0b + QB / 2 - 512;
  sA = sA < 0 ? 0 : (sA > NPTS - 1024 ? NPTS - 1024 : sA);
  if (tid < 1024) t4[tid] = sb[sA + tid];
  for (int i = tid; i <= NBUCK; i += 1024) offL[i] = off[bb * (NBUCK + 1) + i];

  float qx[QW], qy[QW], qz[QW], m2x[QW], m2y[QW], m2z[QW], q2[QW];
  int oq[QW];
#pragma unroll
  for (int qi = 0; qi < QW; ++qi) {
    float4 qp = sb[q0s + qi];
    oq[qi] = ib[q0s + qi];
    qx[qi] = qp.x; qy[qi] = qp.y; qz[qi] = qp.z;
    m2x[qi] = -2.f * qp.x; m2y[qi] = -2.f * qp.y; m2z[qi] = -2.f * qp.z;
    q2[qi] = fmaf(qp.x, qp.x, fmaf(qp.y, qp.y, qp.z * qp.z));
  }
  __syncthreads();

  // ---- pass1: lane minima over slab -> tau (any-subset 20-of-64 bound)
  float m[QW];
#pragma unroll
  for (int qi = 0; qi < QW; ++qi) m[qi] = 3.0e38f;
#pragma unroll 2
  for (int i = 0; i < 16; ++i) {
    float4 c = t4[i * 64 + lane];
#pragma unroll
    for (int qi = 0; qi < QW; ++qi)
      m[qi] = fminf(m[qi], dtilde(m2x[qi], m2y[qi], m2z[qi], c));
  }
  float lo[QW], hi[QW];
#pragma unroll
  for (int qi = 0; qi < QW; ++qi) { lo[qi] = -256.f; hi[qi] = 256.f; }
#pragma unroll 1
  for (int it = 0; it < 24; ++it) {
#pragma unroll
    for (int qi = 0; qi < QW; ++qi) {
      float mid = (lo[qi] + hi[qi]) * 0.5f;
      int c = (int)__popcll(__ballot(m[qi] <= mid));
      if (c >= KNN) hi[qi] = mid; else lo[qi] = mid;
    }
  }

  // ---- certified per-query windows; wave union -> block union
  int e0q[QW], e1q[QW];
  int E0w = NPTS, E1w = 0;
#pragma unroll
  for (int qi = 0; qi < QW; ++qi) {
    float rr = hi[qi] + q2[qi]; rr = rr < 0.f ? 0.f : rr;
    float r = sqrtf(rr) * 1.001f + 1e-4f;
    e0q[qi] = offL[zbucket(qz[qi] - r)];
    e1q[qi] = offL[zbucket(qz[qi] + r) + 1];
    E0w = e0q[qi] < E0w ? e0q[qi] : E0w;
    E1w = e1q[qi] > E1w ? e1q[qi] : E1w;
  }
  if (lane == 0) { ew0[wq] = E0w; ew1[wq] = E1w; }
  __syncthreads();
  int W0 = NPTS, W1 = 0;
#pragma unroll
  for (int k = 0; k < KWAVES; ++k) {
    W0 = ew0[k] < W0 ? ew0[k] : W0;
    W1 = ew1[k] > W1 ? ew1[k] : W1;
  }
  bool fits = (W1 - W0) <= WCAP; // block-uniform
  if (fits) {
    for (int i = tid; i < W1 - W0; i += 1024) t4[i] = sb[W0 + i];
  }
  __syncthreads();

  // ---- pass2: scan this wave's union window, ballot-compact per query.
  // Outside q's own window d~ > tau_q provably, so d~ <= tau_q is the only test.
  int cnt[QW];
#pragma unroll
  for (int qi = 0; qi < QW; ++qi) cnt[qi] = 0;
  int niter = (E1w - E0w + 63) >> 6;
#pragma unroll 1
  for (int i = 0; i < niter; ++i) {
    int j = E0w + i * 64 + lane;
    int jc = j < E1w ? j : E1w - 1;
    float4 c = fits ? t4[jc - W0] : sb[jc];
    bool inb = j < E1w;
#pragma unroll
    for (int qi = 0; qi < QW; ++qi) {
      bool pr = inb && (dtilde(m2x[qi], m2y[qi], m2z[qi], c) <= hi[qi]);
      unsigned long long mk = __ballot(pr);
      if (mk) {
        int ofs = cnt[qi] + (int)__popcll(mk & lmlt);
        if (pr && ofs < CAPC) lidx[wq][qi][ofs] = (unsigned short)j;
        cnt[qi] += (int)__popcll(mk);
      }
    }
  }
  // ---- rare overflow: tighten tau over the window subset and recollect
#pragma unroll 1
  for (int qi = 0; qi < QW; ++qi) {
    if (cnt[qi] > CAPC) {
      float mm = 3.0e38f;
#pragma unroll 1
      for (int i = 0; i < niter; ++i) {
        int j = E0w + i * 64 + lane;
        if (j < E1w) {
          float4 c = fits ? t4[j - W0] : sb[j];
          mm = fminf(mm, dtilde(m2x[qi], m2y[qi], m2z[qi], c));
        }
      }
      float flo = -256.f, fhi = 256.f;
      for (int it = 0; it < 24; ++it) {
        float mid = (flo + fhi) * 0.5f;
        int c = (int)__popcll(__ballot(mm <= mid));
        if (c >= KNN) fhi = mid; else flo = mid;
      }
      hi[qi] = fhi; cnt[qi] = 0;
#pragma unroll 1
      for (int i = 0; i < niter; ++i) {
        int j = E0w + i * 64 + lane;
        bool pr = false;
        if (j < E1w) {
          float4 c = fits ? t4[j - W0] : sb[j];
          pr = dtilde(m2x[qi], m2y[qi], m2z[qi], c) <= fhi;
        }
        unsigned long long mk = __ballot(pr);
        if (mk) {
          int ofs = cnt[qi] + (int)__popcll(mk & lmlt);
          if (pr && ofs < CAPC) lidx[wq][qi][ofs] = (unsigned short)j;
          cnt[qi] += (int)__popcll(mk);
        }
      }
    }
  }

  // ---- exact fp64 rank select, ties -> lower ORIGINAL idx (deterministic)
  double dd[QW]; int ii[QW], ss[QW], cC[QW];
#pragma unroll
  for (int qi = 0; qi < QW; ++qi) {
    cC[qi] = min(cnt[qi], CAPC);
    dd[qi] = 1e300; ii[qi] = -1; ss[qi] = 0;
    if (lane < cC[qi]) {
      int s = lidx[wq][qi][lane];
      float4 c = fits ? t4[s - W0] : sb[s];
      dd[qi] = d2d(qx[qi], qy[qi], qz[qi], c);
      ii[qi] = ib[s];
      ss[qi] = s;
    }
  }
#pragma unroll
  for (int qi = 0; qi < QW; ++qi) {
    int xlo = __double2loint(dd[qi]), xhi = __double2hiint(dd[qi]);
    int r = 0;
#pragma unroll 1
    for (int j = 0; j < cC[qi]; ++j) {
      double dj = __hiloint2double(__builtin_amdgcn_readlane(xhi, j),
                                   __builtin_amdgcn_readlane(xlo, j));
      int idj = __builtin_amdgcn_readlane(ii[qi], j);
      r += (dj < dd[qi]) || (dj == dd[qi] && idj < ii[qi]);
    }
    if (ii[qi] >= 0 && r < KNN) nsel[wq][qi][r] = ss[qi] | (ii[qi] << 16);
  }

  // ---- fused feat + conv + BN/leaky + max-over-k (lane = output channel)
  float wd  = w[lane * EDIM + 192];
  float wld = w[lane * EDIM + 193];
  float wrh = w[lane * EDIM + 194];
  float wdv = w[lane * EDIM + 195];
  float wa  = w[lane * EDIM + 196];
  float sc = gamma[lane] * __builtin_amdgcn_rcpf(__builtin_amdgcn_sqrtf(var[lane] + 1e-5f));
  float muv = mean[lane], bt = beta[lane];
#pragma unroll 1
  for (int qi = 0; qi < QW; ++qi) {
    int pv = nsel[wq][qi][lane < KNN ? lane : 0];
    int js = pv & 0xFFFF;
    float4 nb = fits ? t4[js - W0] : sb[js];
    float vx = nb.x - qx[qi], vy = nb.y - qy[qi], vz = nb.z - qz[qi];
    float dist = __builtin_amdgcn_sqrtf(fmaf(vx, vx, fmaf(vy, vy, vz * vz)));
    float inv = __builtin_amdgcn_rcpf(dist + 1e-6f);
    float vnx = vx * inv, vny = vy * inv, vnz = vz * inv;
    float msk = (lane < KNN) ? 1.f : 0.f;
    float sd = wsum(dist * msk);
    float szn = wsum(nb.z * msk);
    float sx = wsum(vnx * msk);
    float sy = wsum(vny * msk);
    float s3 = wsum(vnz * msk);
    float ld = sd * (1.f / KNN);
    float rh = qz[qi] - szn * (1.f / KNN);
    float dev = dist - ld;
    float dvs = wsum(dev * dev * msk);
    float dv = dvs * (1.f / (KNN - 1));
    float mdx = sx * (1.f / KNN), mdy = sy * (1.f / KNN), mdz = s3 * (1.f / KNN);
    float mnorm = __builtin_amdgcn_sqrtf(fmaf(mdx, mdx, fmaf(mdy, mdy, mdz * mdz)));
    float rinv2 = __builtin_amdgcn_rcpf(mnorm + 1e-6f);
    mdx *= rinv2; mdy *= rinv2; mdz *= rinv2;
    float cosv = vnx * mdx + vny * mdy + vnz * mdz;
    float angle = 1.f - fabsf(cosv);
    float base = projc[(size_t)(bb * NPTS + oq[qi]) * 64 + lane]
               + ld * wld + rh * wrh + dv * wdv;
    float zmax = -3.0e38f, zmin = 3.0e38f;
#pragma unroll
    for (int kk = 0; kk < KNN; ++kk) {
      float dk = bcastf(dist, kk);
      float ak = bcastf(angle, kk);
      int jk = __builtin_amdgcn_readlane(pv, kk) >> 16; // orig neighbor id
      float z = base + projn[(size_t)(bb * NPTS + jk) * 64 + lane] + dk * wd + ak * wa;
      zmax = fmaxf(zmax, z);
      zmin = fminf(zmin, z);
    }
    float M = (sc >= 0.f) ? zmax : zmin; // BN-scale sign-aware monotone epilogue
    float yv = (M - muv) * sc + bt;
    yv = (yv >= 0.f) ? yv : 0.2f * yv;
    // coalesced: 64 lanes write one contiguous 256B row per query
    scratch[(size_t)(bb * NPTS + q0s + qi) * 64 + lane] = yv;
  }
}

// scratch[b][slot][o] -> out[b][o][n]  (slot = rinv[n]); L2-resident permute
__global__ __launch_bounds__(256) void permute_kernel(const float* __restrict__ scratch,
                                                      const int* __restrict__ rinv,
                                                      float* __restrict__ out) {
  __shared__ float tile[64][65];
  int tid = threadIdx.x, lane = tid & 63, grp = tid >> 6;
  int blk = blockIdx.x; // 256: bb = blk>>7, n-tile = (blk&127)*64
  int bb = blk >> 7;
  int n0 = (blk & 127) * 64;
  int slot = rinv[bb * NPTS + n0 + lane];
  const float4* row = (const float4*)(scratch + (size_t)(bb * NPTS + slot) * 64);
#pragma unroll
  for (int c4 = 0; c4 < 4; ++c4) {
    float4 v = row[grp * 4 + c4];
    tile[lane][grp * 16 + c4 * 4 + 0] = v.x;
    tile[lane][grp * 16 + c4 * 4 + 1] = v.y;
    tile[lane][grp * 16 + c4 * 4 + 2] = v.z;
    tile[lane][grp * 16 + c4 * 4 + 3] = v.w;
  }
  __syncthreads();
#pragma unroll
  for (int r16 = 0; r16 < 16; ++r16) {
    int o = grp * 16 + r16;
    out[((size_t)bb * CH + o) * NPTS + n0 + lane] = tile[lane][o];
  }
}

extern "C" void kernel_launch(void* const* d_in, const int* in_sizes, int n_in,
                              void* d_out, int out_size, void* d_ws, size_t ws_size,
                              hipStream_t stream) {
  const float* x = (const float*)d_in[0];
  const float* w = (const float*)d_in[1];
  const float* gamma = (const float*)d_in[2];
  const float* beta = (const float*)d_in[3];
  const float* mean = (const float*)d_in[4];
  const float* var = (const float*)d_in[5];
  float* out = (float*)d_out;

  // workspace layout
  const size_t OFF_CPACK = 0;          // 262144
  const size_t OFF_PROJC = 262144;     // 4 MiB
  const size_t OFF_PROJN = 4456448;    // 4 MiB
  const size_t OFF_S4    = 8650752;    // 262144
  const size_t OFF_SIDX  = 8912896;    // 65536
  const size_t OFF_RINV  = 8978432;    // 65536
  const size_t OFF_HIST  = 9043968;    // 8192
  const size_t OFF_OFFT  = 9052160;    // 8200 (+pad)
  const size_t OFF_CUR   = 9060864;    // 8192
  const size_t OFF_SCR   = 9069056;    // 4 MiB
  const size_t NEED      = 9069056 + 4194304;
  if (ws_size < NEED) return;

  char* ws = (char*)d_ws;
  float4* cpack = (float4*)(ws + OFF_CPACK);
  float* projc = (float*)(ws + OFF_PROJC);
  float* projn = (float*)(ws + OFF_PROJN);
  float4* s4g = (float4*)(ws + OFF_S4);
  int* sidxg = (int*)(ws + OFF_SIDX);
  int* rinv = (int*)(ws + OFF_RINV);
  int* hist = (int*)(ws + OFF_HIST);
  int* offt = (int*)(ws + OFF_OFFT);
  int* cur = (int*)(ws + OFF_CUR);
  float* scr = (float*)(ws + OFF_SCR);

  zeroh_kernel<<<2, 1024, 0, stream>>>(hist);
  proj_kernel<<<dim3(64, 8), 256, 0, stream>>>(x, w, cpack, projc, projn, hist);
  prefix_kernel<<<NBATCH, 1024, 0, stream>>>(hist, offt, cur);
  scatter_kernel<<<64, 256, 0, stream>>>(cpack, cur, s4g, sidxg, rinv);
  knnfeat_kernel<<<512, 1024, 0, stream>>>(s4g, sidxg, offt, projc, projn, w,
                                           gamma, beta, mean, var, scr);
  permute_kernel<<<256, 256, 0, stream>>>(scr, rinv, out);
}

// Round 12
// 79.449 us; speedup vs baseline: 2.2779x; 2.2779x over previous
//
#include <hip/hip_runtime.h>

// EdgeConv (B=2, N=8192, C=64, K=20, OUT=64):
//  proj    -> per-point 64->64 projections (8-way split over mat x out-quarter;
//             builds combined weights (w1-w2),(w2+w3) in LDS from w directly;
//             by==0 blocks also pack cpack = (x,y,z,|c|^2))
//  knnfeat -> fused, 1024 threads (16 waves x 4 queries; 4 waves/SIMD and
//             ~16 VALU ops per ds_read_b128 -- the verified balance point).
//             MEASURED LOCAL OPTIMUM: all six structural perturbations tested
//             in rounds 5-11 regressed (atomic-append +39us, QW8 +33us,
//             pk_fma +16us, global-window +69us, LDS-window +54us,
//             forced-occupancy +94us). Do not perturb without new evidence.
//             pass1: lane bin-minima of d~ = |c|^2 - 2 q.c (3 fma) ->
//                    tau >= d~_(20) via 24-step float bisection (ballot count)
//             pass2: ballot-compact (<=64) candidates with d~ <= tau
//             exact fp64 rank select (readlane broadcast, ties -> lower idx)
//             feat: edge features + gathered projections + BN/leaky/max,
//                   swizzled LDS transpose stage -> coalesced float4 out.

#define NPTS 8192
#define NBATCH 2
#define NQ (NBATCH * NPTS)
#define CH 64
#define KNN 20
#define EDIM 197
#define QW 4             // queries per wave
#define KWAVES 16        // waves per block (1024 threads)
#define QB (QW * KWAVES) // 64 queries per block
#define CAPC 64          // collected-candidate capacity (mean ~24)

__device__ __forceinline__ float wsum(float v) {
  v += __shfl_xor(v, 1, 64);
  v += __shfl_xor(v, 2, 64);
  v += __shfl_xor(v, 4, 64);
  v += __shfl_xor(v, 8, 64);
  v += __shfl_xor(v, 16, 64);
  v += __shfl_xor(v, 32, 64);
  return v;
}

// monotone-shifted distance surrogate: d~ = |c|^2 - 2 q.c  (= d^2 - |q|^2 exact)
// identical fmaf chain in both passes -> bitwise-consistent
__device__ __forceinline__ float dtilde(float m2x, float m2y, float m2z, float4 c) {
  return fmaf(m2x, c.x, fmaf(m2y, c.y, fmaf(m2z, c.z, c.w)));
}

// exact-enough fp64 true distance (fp32 diffs exact in fp64, squares exact)
__device__ __forceinline__ double d2d(float qx, float qy, float qz, float4 c) {
  double dx = (double)qx - (double)c.x;
  double dy = (double)qy - (double)c.y;
  double dz = (double)qz - (double)c.z;
  return dx * dx + dy * dy + dz * dz;
}

__device__ __forceinline__ float bcastf(float v, int l) {
  return __int_as_float(__builtin_amdgcn_readlane(__float_as_int(v), l));
}

// blockIdx.y in [0,8): mat = by>>2, output-quarter = by&3 (16 channels each).
// by==0 blocks additionally pack cpack (xyz + |c|^2).
__global__ __launch_bounds__(256) void proj_kernel(const float* __restrict__ x,
                                                   const float* __restrict__ w,
                                                   float4* __restrict__ cpack,
                                                   float* __restrict__ projc,
                                                   float* __restrict__ projn) {
  __shared__ float wl[CH * 16];
  int by = blockIdx.y;
  int mat = by >> 2, oq = by & 3;
  for (int i = threadIdx.x; i < CH * 16; i += 256) {
    int c = i >> 4, oo = i & 15;
    int o = oq * 16 + oo;
    float w1 = w[o * EDIM + c];
    float w2 = w[o * EDIM + 64 + c];
    float w3 = w[o * EDIM + 128 + c];
    wl[i] = mat ? (w2 + w3) : (w1 - w2);
  }
  __syncthreads();
  int p = blockIdx.x * 256 + threadIdx.x;
  int b = p >> 13, n = p & (NPTS - 1);
  const float* xb = x + (size_t)b * CH * NPTS + n;
  float acc[16];
#pragma unroll
  for (int o = 0; o < 16; ++o) acc[o] = 0.f;
#pragma unroll 4
  for (int c = 0; c < CH; ++c) {
    float xv = xb[(size_t)c * NPTS]; // coalesced across threads
    const float4* wr = (const float4*)(wl + c * 16); // uniform -> broadcast
#pragma unroll
    for (int o4 = 0; o4 < 4; ++o4) {
      float4 wv = wr[o4];
      acc[o4 * 4 + 0] = fmaf(wv.x, xv, acc[o4 * 4 + 0]);
      acc[o4 * 4 + 1] = fmaf(wv.y, xv, acc[o4 * 4 + 1]);
      acc[o4 * 4 + 2] = fmaf(wv.z, xv, acc[o4 * 4 + 2]);
      acc[o4 * 4 + 3] = fmaf(wv.w, xv, acc[o4 * 4 + 3]);
    }
  }
  float* dst = (mat ? projn : projc) + (size_t)p * 64 + oq * 16;
#pragma unroll
  for (int o4 = 0; o4 < 4; ++o4)
    ((float4*)dst)[o4] = make_float4(acc[o4 * 4 + 0], acc[o4 * 4 + 1],
                                     acc[o4 * 4 + 2], acc[o4 * 4 + 3]);
  if (by == 0) {
    float cx = xb[0], cy = xb[(size_t)NPTS], cz = xb[(size_t)2 * NPTS];
    cpack[p] = make_float4(cx, cy, cz, fmaf(cx, cx, fmaf(cy, cy, cz * cz)));
  }
}

__global__ __launch_bounds__(1024) void knnfeat_kernel(const float4* __restrict__ cpack,
                                                       const float* __restrict__ projc,
                                                       const float* __restrict__ projn,
                                                       const float* __restrict__ w,
                                                       const float* __restrict__ gamma,
                                                       const float* __restrict__ beta,
                                                       const float* __restrict__ mean,
                                                       const float* __restrict__ var,
                                                       float* __restrict__ out) {
  __shared__ float4 t4[NPTS];             // 128 KB, live for whole kernel
  __shared__ int lidx[KWAVES][QW][CAPC];  // 16 KB; reused as zbuf (per-wave rows)
  __shared__ int nsel[KWAVES][QW][KNN];   // 5 KB
  int tid = threadIdx.x;
  int lane = tid & 63;
  int wq = tid >> 6;            // wave 0..15
  int blk = blockIdx.x;         // 256 blocks (1 per CU)
  int bb = blk >> 7;            // batch
  int q0 = blk * QB + wq * QW;  // this wave's 4 queries
  const float4* cb = cpack + bb * NPTS;

  for (int i = tid; i < NPTS; i += 1024) t4[i] = cb[i];
  float qx[QW], qy[QW], qz[QW], m2x[QW], m2y[QW], m2z[QW];
#pragma unroll
  for (int qi = 0; qi < QW; ++qi) {
    float4 qp = cpack[q0 + qi];
    qx[qi] = qp.x; qy[qi] = qp.y; qz[qi] = qp.z;
    m2x[qi] = -2.f * qp.x; m2y[qi] = -2.f * qp.y; m2z[qi] = -2.f * qp.z;
  }
  __syncthreads();

  // ---- pass 1: per-lane bin minima of d~ (128 candidates per lane)
  float m[QW];
#pragma unroll
  for (int qi = 0; qi < QW; ++qi) m[qi] = 3.0e38f;
#pragma unroll 2
  for (int i = 0; i < NPTS / 64; ++i) {
    float4 c = t4[lane + i * 64];
#pragma unroll
    for (int qi = 0; qi < QW; ++qi)
      m[qi] = fminf(m[qi], dtilde(m2x[qi], m2y[qi], m2z[qi], c));
  }
  // tau >= 20th-smallest lane-min (>= global d~_(20)) via float bisection.
  // Invariant: count(m <= hi) >= KNN. |d~| <= |c|^2+2|q||c| < 100 << 256.
  float lo[QW], hi[QW];
#pragma unroll
  for (int qi = 0; qi < QW; ++qi) { lo[qi] = -256.f; hi[qi] = 256.f; }
#pragma unroll 1
  for (int it = 0; it < 24; ++it) {
#pragma unroll
    for (int qi = 0; qi < QW; ++qi) {
      float mid = (lo[qi] + hi[qi]) * 0.5f;
      int c = (int)__popcll(__ballot(m[qi] <= mid));
      if (c >= KNN) hi[qi] = mid; else lo[qi] = mid;
    }
  }

  // ---- pass 2: ballot-compact candidates with d~ <= tau (~24 expected/query)
  int cnt[QW];
#pragma unroll
  for (int qi = 0; qi < QW; ++qi) cnt[qi] = 0;
  unsigned long long lmlt = (1ull << lane) - 1ull;
#pragma unroll 2
  for (int i = 0; i < NPTS / 64; ++i) {
    float4 c = t4[lane + i * 64];
#pragma unroll
    for (int qi = 0; qi < QW; ++qi) {
      bool pr = dtilde(m2x[qi], m2y[qi], m2z[qi], c) <= hi[qi];
      unsigned long long mk = __ballot(pr);
      if (mk) { // skipped ~83% of (iter,query) pairs
        int ofs = cnt[qi] + (int)__popcll(mk & lmlt);
        if (pr && ofs < CAPC) lidx[wq][qi][ofs] = lane + i * 64;
        cnt[qi] += (int)__popcll(mk);
      }
    }
  }

  // ---- exact fp64 rank select: one candidate per lane, readlane broadcast
  double dd[QW]; int ii[QW]; int cC[QW];
#pragma unroll
  for (int qi = 0; qi < QW; ++qi) {
    cC[qi] = min(cnt[qi], CAPC);
    dd[qi] = 1e300; ii[qi] = -1;
    if (lane < cC[qi]) {
      int id = lidx[wq][qi][lane];
      dd[qi] = d2d(qx[qi], qy[qi], qz[qi], t4[id]);
      ii[qi] = id;
    }
  }
#pragma unroll
  for (int qi = 0; qi < QW; ++qi) {
    int xlo = __double2loint(dd[qi]), xhi = __double2hiint(dd[qi]);
    int r = 0;
#pragma unroll 1
    for (int j = 0; j < cC[qi]; ++j) {
      double dj = __hiloint2double(__builtin_amdgcn_readlane(xhi, j),
                                   __builtin_amdgcn_readlane(xlo, j));
      int idj = __builtin_amdgcn_readlane(ii[qi], j);
      r += (dj < dd[qi]) || (dj == dd[qi] && idj < ii[qi]);
    }
    if (ii[qi] >= 0 && r < KNN) nsel[wq][qi][r] = ii[qi];
  }

  // ---- fused feature + conv + BN/leaky + max-over-k epilogue
  float* zbuf = (float*)&lidx[0][0][0]; // per-wave region == own dead lidx rows
  float wd  = w[lane * EDIM + 192];
  float wld = w[lane * EDIM + 193];
  float wrh = w[lane * EDIM + 194];
  float wdv = w[lane * EDIM + 195];
  float wa  = w[lane * EDIM + 196];
  float sc = gamma[lane] / sqrtf(var[lane] + 1e-5f);
  float muv = mean[lane], bt = beta[lane];
#pragma unroll 2
  for (int qi = 0; qi < QW; ++qi) {
    int gq = q0 + qi;
    int jj = nsel[wq][qi][lane < KNN ? lane : 0] & (NPTS - 1);
    float4 nb = t4[jj];
    float vx = nb.x - qx[qi], vy = nb.y - qy[qi], vz = nb.z - qz[qi];
    float dist = sqrtf(fmaf(vx, vx, fmaf(vy, vy, vz * vz)));
    float inv = 1.f / (dist + 1e-6f);
    float vnx = vx * inv, vny = vy * inv, vnz = vz * inv;
    float msk = (lane < KNN) ? 1.f : 0.f;
    float sd = wsum(dist * msk);
    float szn = wsum(nb.z * msk);
    float sx = wsum(vnx * msk);
    float sy = wsum(vny * msk);
    float s3 = wsum(vnz * msk);
    float ld = sd * (1.f / KNN);
    float rh = qz[qi] - szn * (1.f / KNN);
    float dev = dist - ld;
    float dvs = wsum(dev * dev * msk);
    float dv = dvs * (1.f / (KNN - 1));
    float mdx = sx * (1.f / KNN), mdy = sy * (1.f / KNN), mdz = s3 * (1.f / KNN);
    float mnorm = sqrtf(fmaf(mdx, mdx, fmaf(mdy, mdy, mdz * mdz)));
    float rinv = 1.f / (mnorm + 1e-6f);
    mdx *= rinv; mdy *= rinv; mdz *= rinv;
    float cosv = vnx * mdx + vny * mdy + vnz * mdz;
    float angle = 1.f - fabsf(cosv);
    float base = projc[(size_t)gq * 64 + lane] + ld * wld + rh * wrh + dv * wdv;
    float zmax = -3.0e38f, zmin = 3.0e38f;
#pragma unroll
    for (int kk = 0; kk < KNN; ++kk) {
      float dk = bcastf(dist, kk);
      float ak = bcastf(angle, kk);
      int jk = __builtin_amdgcn_readlane(jj, kk);
      float z = base + projn[(size_t)(bb * NPTS + jk) * 64 + lane] + dk * wd + ak * wa;
      zmax = fmaxf(zmax, z);
      zmin = fminf(zmin, z);
    }
    float M = (sc >= 0.f) ? zmax : zmin; // BN scale sign-aware (monotone epilogue)
    float yv = (M - muv) * sc + bt;
    yv = (yv >= 0.f) ? yv : 0.2f * yv;
    int qcol = wq * QW + qi;
    zbuf[qcol * 64 + ((lane + qcol) & 63)] = yv; // swizzled: conflict-free both ways
  }
  __syncthreads();
  // cooperative transpose writeout: out[b][o][n0..n0+63]
  {
    int o = tid >> 4, g = tid & 15;
    int n0 = (blk & 127) * 64;
    int q4 = g * 4;
    float4 v;
    v.x = zbuf[(q4 + 0) * 64 + ((o + q4 + 0) & 63)];
    v.y = zbuf[(q4 + 1) * 64 + ((o + q4 + 1) & 63)];
    v.z = zbuf[(q4 + 2) * 64 + ((o + q4 + 2) & 63)];
    v.w = zbuf[(q4 + 3) * 64 + ((o + q4 + 3) & 63)];
    *(float4*)(out + (size_t)bb * CH * NPTS + (size_t)o * NPTS + n0 + q4) = v;
  }
}

extern "C" void kernel_launch(void* const* d_in, const int* in_sizes, int n_in,
                              void* d_out, int out_size, void* d_ws, size_t ws_size,
                              hipStream_t stream) {
  const float* x = (const float*)d_in[0];
  const float* w = (const float*)d_in[1];
  const float* gamma = (const float*)d_in[2];
  const float* beta = (const float*)d_in[3];
  const float* mean = (const float*)d_in[4];
  const float* var = (const float*)d_in[5];
  float* out = (float*)d_out;

  // workspace layout
  const size_t OFF_CPACK = 0;                 // 262144 B
  const size_t OFF_PROJC = 262144;            // 4 MiB
  const size_t OFF_PROJN = 262144 + 4194304;  // 4 MiB
  const size_t NEED = 262144 + 8388608;
  if (ws_size < NEED) return;

  char* ws = (char*)d_ws;
  float4* cpack = (float4*)(ws + OFF_CPACK);
  float* projc = (float*)(ws + OFF_PROJC);
  float* projn = (float*)(ws + OFF_PROJN);

  proj_kernel<<<dim3(64, 8), 256, 0, stream>>>(x, w, cpack, projc, projn);
  knnfeat_kernel<<<256, 1024, 0, stream>>>(cpack, projc, projn, w,
                                           gamma, beta, mean, var, out);
}